// Round 1
// baseline (14478.162 us; speedup 1.0000x reference)
//
#include <hip/hip_runtime.h>

// ComplexModel: 2-layer LSTM (B=64,T=256,D=512,H=1024) + FC head, MI355X gfx950.
// Strategy: fp16-input / fp32-accum MFMA 16x16x32; persistent 256-block kernel per
// LSTM layer with hand-rolled agent-scope grid barrier (1 block/CU => co-residency
// guaranteed by LDS capacity, no cooperative launch needed); weights folded into the
// per-step matmul (K = D+H or H+H); gate columns pre-permuted (4c+g) so each block's
// 16 gate cols are one MFMA n-tile and i/f/g/o are wave-local.

#define NB 256
#define NT 256

typedef _Float16 f16x8 __attribute__((ext_vector_type(8)));
typedef float f32x4 __attribute__((ext_vector_type(4)));

__device__ __forceinline__ float sigm(float x)   { return 1.0f / (1.0f + __expf(-x)); }
__device__ __forceinline__ float tanh_f(float x) { return 1.0f - 2.0f / (__expf(2.0f * x) + 1.0f); }

// ---------------- prep kernels ----------------

__global__ void prep_x_kernel(const float* __restrict__ x, _Float16* __restrict__ xh, int n) {
  int i = blockIdx.x * blockDim.x + threadIdx.x;
  if (i < n) xh[i] = (_Float16)x[i];
}

// Build MFMA B-fragment layout: dst[((nt*(K/32)+kb)*64 + lane)*8 + j] =
//   src[k = kb*32 + (lane>>4)*8 + j][col = perm(nt*16 + (lane&15))]
// B operand layout for mfma_f32_16x16x32_f16: lane supplies B[k=(lane>>4)*8+j][n=lane&15].
__global__ void swizzle_b_kernel(const float* __restrict__ src0, const float* __restrict__ src1,
                                 int k0, int K, int N, int srcStride, int permute,
                                 _Float16* __restrict__ dst) {
  int id = blockIdx.x * blockDim.x + threadIdx.x;
  int total = (N / 16) * (K / 32) * 64;
  if (id >= total) return;
  int lane = id & 63;
  int kb = (id >> 6) % (K / 32);
  int nt = id / ((K / 32) * 64);
  int kbase = kb * 32 + ((lane >> 4) << 3);
  int pc = nt * 16 + (lane & 15);
  int oc = permute ? ((pc & 3) * 1024 + (pc >> 2)) : pc;   // pc = 4*hcol + gate
  f16x8 v;
  #pragma unroll
  for (int j = 0; j < 8; ++j) {
    int k = kbase + j;
    float f = (k < k0) ? src0[(size_t)k * srcStride + oc]
                       : src1[(size_t)(k - k0) * srcStride + oc];
    v[j] = (_Float16)f;
  }
  ((f16x8*)dst)[id] = v;
}

__global__ void prep_small_kernel(const float* __restrict__ b1, const float* __restrict__ b2,
                                  const float* __restrict__ h0, const float* __restrict__ c0,
                                  float* __restrict__ b1p, float* __restrict__ b2p,
                                  _Float16* __restrict__ ys1_0, float* __restrict__ cbuf,
                                  int* __restrict__ bar) {
  int i = blockIdx.x * blockDim.x + threadIdx.x;
  if (i < 4096) {
    int oc = (i & 3) * 1024 + (i >> 2);
    b1p[i] = b1[oc];
    b2p[i] = b2[oc];
  }
  if (i < 65536) { ys1_0[i] = (_Float16)h0[i]; cbuf[i] = c0[i]; }
  if (i < 512) bar[i] = 0;
}

// ---------------- grid barrier (2-level tree, agent scope) ----------------
// bar[g*32] g=0..7 : group counters (separate 128B lines); bar[256]: root; bar[288]: generation.
__device__ __forceinline__ void grid_barrier(int* bar) {
  __syncthreads();                 // compiler emits vmcnt(0) drain before s_barrier
  if (threadIdx.x == 0) {
    __threadfence();               // make this block's h/c stores agent-visible
    int g = __hip_atomic_load(&bar[288], __ATOMIC_RELAXED, __HIP_MEMORY_SCOPE_AGENT);
    int grp = (blockIdx.x >> 5) << 5;
    int old = __hip_atomic_fetch_add(&bar[grp], 1, __ATOMIC_ACQ_REL, __HIP_MEMORY_SCOPE_AGENT);
    if (old == 31) {
      int r = __hip_atomic_fetch_add(&bar[256], 1, __ATOMIC_ACQ_REL, __HIP_MEMORY_SCOPE_AGENT);
      if (r == 7) {
        #pragma unroll
        for (int i = 0; i < 8; ++i)
          __hip_atomic_store(&bar[i * 32], 0, __ATOMIC_RELAXED, __HIP_MEMORY_SCOPE_AGENT);
        __hip_atomic_store(&bar[256], 0, __ATOMIC_RELAXED, __HIP_MEMORY_SCOPE_AGENT);
        __hip_atomic_store(&bar[288], g + 1, __ATOMIC_RELEASE, __HIP_MEMORY_SCOPE_AGENT);
      }
    }
    while (__hip_atomic_load(&bar[288], __ATOMIC_RELAXED, __HIP_MEMORY_SCOPE_AGENT) == g)
      __builtin_amdgcn_s_sleep(2);
    (void)__hip_atomic_load(&bar[288], __ATOMIC_ACQUIRE, __HIP_MEMORY_SCOPE_AGENT);
  }
  __syncthreads();
}

// ---------------- persistent LSTM layer ----------------
// Block blk owns h-cols [4*blk, 4*blk+4) i.e. permuted gate cols [16*blk, 16*blk+16) (one n-tile).
// Wave w handles batches [16w,16w+16) (one m-tile). K = kxb*32 (x part) + 1024 (h part).
// U-part B-fragments staged in LDS once (t-invariant); x-part B read from global (L1/L2-cached).
__launch_bounds__(NT, 1)
__global__ void lstm_layer_kernel(const _Float16* __restrict__ xsrc, size_t xts, size_t xbs, int kxb,
                                  _Float16* hseq, const _Float16* __restrict__ hinit,
                                  const _Float16* __restrict__ bfrag, const float* __restrict__ biasp,
                                  float* __restrict__ cbuf, int* bar) {
  __shared__ _Float16 Bs[32 * 512];    // 32 KB: U-part B fragments
  __shared__ float gt[4][16 * 17];     // per-wave gate tile for i/f/g/o regroup
  const int tid = threadIdx.x;
  const int lane = tid & 63;
  const int w = tid >> 6;
  const int blk = blockIdx.x;
  const int KB = kxb + 32;

  {  // stage the h-part (U) B-fragments for this block's n-tile
    const uint4* s = (const uint4*)(bfrag + (size_t)blk * KB * 512 + (size_t)kxb * 512);
    uint4* d = (uint4*)Bs;
    for (int i = tid; i < 32 * 64; i += NT) d[i] = s[i];
  }
  __syncthreads();

  const f16x8* Bxg = (const f16x8*)(bfrag + (size_t)blk * KB * 512);  // x-part B (global)
  const f16x8* Bv  = (const f16x8*)Bs;                                // h-part B (LDS)
  const int brow = (w << 4) + (lane & 15);     // A row (batch) this lane supplies
  const int kq8  = (lane >> 4) << 3;           // k offset within 32-k block
  const int rr = lane & 15;                    // cell-update: batch-within-tile
  const int hh = lane >> 4;                    // cell-update: hcol-within-block (0..3)
  const int hcol = (blk << 2) + hh;
  const int cidx = ((w << 4) + rr) * 1024 + hcol;
  const float bias = biasp[(blk << 4) + (lane & 15)];
  float* g = &gt[w][0];

  for (int t = 0; t < 256; ++t) {
    f32x4 acc = {bias, bias, bias, bias};
    const f16x8* ax = (const f16x8*)(xsrc + (size_t)t * xts + (size_t)brow * xbs + kq8);
    #pragma unroll 8
    for (int kb = 0; kb < kxb; ++kb)
      acc = __builtin_amdgcn_mfma_f32_16x16x32_f16(ax[kb * 4], Bxg[kb * 64 + lane], acc, 0, 0, 0);
    const _Float16* hb = (t == 0) ? hinit : (hseq + (size_t)t * 65536);
    const f16x8* ah = (const f16x8*)(hb + (size_t)brow * 1024 + kq8);
    #pragma unroll 8
    for (int kb = 0; kb < 32; ++kb)
      acc = __builtin_amdgcn_mfma_f32_16x16x32_f16(ah[kb * 4], Bv[kb * 64 + lane], acc, 0, 0, 0);

    // C layout: col = lane&15, row = (lane>>4)*4 + r  -> park in LDS, regroup i/f/g/o per cell
    #pragma unroll
    for (int r = 0; r < 4; ++r) g[((hh << 2) + r) * 17 + rr] = acc[r];
    __syncthreads();
    float iv = g[rr * 17 + (hh << 2) + 0];
    float fv = g[rr * 17 + (hh << 2) + 1];
    float gv = g[rr * 17 + (hh << 2) + 2];
    float ov = g[rr * 17 + (hh << 2) + 3];
    float c_old = cbuf[cidx];
    float cn = sigm(fv) * c_old + sigm(iv) * tanh_f(gv);
    float hn = sigm(ov) * tanh_f(cn);
    cbuf[cidx] = cn;
    hseq[(size_t)(t + 1) * 65536 + cidx] = (_Float16)hn;
    grid_barrier(bar);
  }
}

// ---------------- FC head ----------------

// Y1[b][u][j] = ys2[u+1][b][:] @ fc1_w[:, j] + fc1_b[j]   (16384x1024 @ 1024x512)
__launch_bounds__(256, 1)
__global__ void fc1_gemm_kernel(const _Float16* __restrict__ ys2, const _Float16* __restrict__ wfrag,
                                const float* __restrict__ fc1b, float* __restrict__ Y1) {
  const int mb = blockIdx.x >> 3;
  const int nb = blockIdx.x & 7;
  const int tid = threadIdx.x;
  const int lane = tid & 63;
  const int w = tid >> 6;
  const int R0 = mb * 64 + w * 16;
  const int arow = R0 + (lane & 15);           // row = u*64 + b
  const int u = arow >> 6;
  const int b = arow & 63;
  const f16x8* A = (const f16x8*)(ys2 + (size_t)(u + 1) * 65536 + (size_t)b * 1024 + ((lane >> 4) << 3));
  const f16x8* W = (const f16x8*)wfrag;
  f32x4 acc[4];
  #pragma unroll
  for (int n = 0; n < 4; ++n) acc[n] = (f32x4){0.f, 0.f, 0.f, 0.f};
  #pragma unroll 4
  for (int kb = 0; kb < 32; ++kb) {
    f16x8 a = A[kb * 4];
    #pragma unroll
    for (int n = 0; n < 4; ++n)
      acc[n] = __builtin_amdgcn_mfma_f32_16x16x32_f16(a, W[(((nb * 4 + n) * 32) + kb) * 64 + lane],
                                                      acc[n], 0, 0, 0);
  }
  const int rb = R0 + ((lane >> 4) << 2);
  #pragma unroll
  for (int n = 0; n < 4; ++n) {
    int col = nb * 64 + n * 16 + (lane & 15);
    float bias = fc1b[col];
    #pragma unroll
    for (int r = 0; r < 4; ++r) {
      int R = rb + r;
      Y1[((size_t)(R & 63) * 256 + (R >> 6)) * 512 + col] = acc[n][r] + bias;
    }
  }
}

// FC2 partial reduction: 256 K-chunks of 512; part[kc][b][36]
__global__ void fc2_partial_kernel(const float* __restrict__ Y1, const float* __restrict__ fc2w,
                                   float* __restrict__ part) {
  int kc = blockIdx.x;
  int tid = threadIdx.x;
  int b = tid >> 2, q = tid & 3;
  const float* y = Y1 + (size_t)b * 131072 + (size_t)kc * 512;
  const float* wbase = fc2w + (size_t)kc * 512 * 36 + q * 9;
  float acc[9];
  #pragma unroll
  for (int j = 0; j < 9; ++j) acc[j] = 0.f;
  for (int k = 0; k < 512; ++k) {
    float yv = y[k];
    const float* wr = wbase + (size_t)k * 36;
    #pragma unroll
    for (int j = 0; j < 9; ++j) acc[j] = fmaf(yv, wr[j], acc[j]);
  }
  float* o = part + ((size_t)kc * 64 + b) * 36 + q * 9;
  #pragma unroll
  for (int j = 0; j < 9; ++j) o[j] = acc[j];
}

__global__ void fc_final_kernel(const float* __restrict__ part, const float* __restrict__ fc2b,
                                const float* __restrict__ fc3w, const float* __restrict__ fc3b,
                                const float* __restrict__ fc4w, const float* __restrict__ fc4b,
                                float* __restrict__ out) {
  __shared__ float z2[64 * 36];
  __shared__ float z3[64 * 6];
  int tid = threadIdx.x;  // 384
  for (int idx = tid; idx < 64 * 36; idx += 384) {
    int b = idx / 36, m = idx % 36;
    float s = fc2b[m];
    for (int kc = 0; kc < 256; ++kc) s += part[((size_t)kc * 64 + b) * 36 + m];
    z2[idx] = s;
  }
  __syncthreads();
  {
    int b = tid / 6, n = tid % 6;
    float s = fc3b[n];
    #pragma unroll 4
    for (int m = 0; m < 36; ++m) s += z2[b * 36 + m] * fc3w[m * 6 + n];
    z3[tid] = s;
  }
  __syncthreads();
  {
    int b = tid / 6, n = tid % 6;
    float s = fc4b[n];
    #pragma unroll
    for (int m = 0; m < 6; ++m) s += z3[b * 6 + m] * fc4w[m * 6 + n];
    out[tid] = fmaxf(s, 0.0f);
  }
}

// ---------------- host ----------------

extern "C" void kernel_launch(void* const* d_in, const int* in_sizes, int n_in,
                              void* d_out, int out_size, void* d_ws, size_t ws_size,
                              hipStream_t stream) {
  const float* x    = (const float*)d_in[0];
  const float* h0   = (const float*)d_in[1];
  const float* c0   = (const float*)d_in[2];
  const float* W1   = (const float*)d_in[3];
  const float* U1   = (const float*)d_in[4];
  const float* b1   = (const float*)d_in[5];
  const float* W2   = (const float*)d_in[6];
  const float* U2   = (const float*)d_in[7];
  const float* b2   = (const float*)d_in[8];
  const float* fc1w = (const float*)d_in[9];
  const float* fc1b = (const float*)d_in[10];
  const float* fc2w = (const float*)d_in[11];
  const float* fc2b = (const float*)d_in[12];
  const float* fc3w = (const float*)d_in[13];
  const float* fc3b = (const float*)d_in[14];
  const float* fc4w = (const float*)d_in[15];
  const float* fc4b = (const float*)d_in[16];
  float* out = (float*)d_out;

  char* p = (char*)d_ws;
  auto alloc = [&](size_t bytes) { char* r = p; p += (bytes + 255) & ~(size_t)255; return r; };
  _Float16* xh    = (_Float16*)alloc(8388608ull * 2);        // x as f16, [b][t][d]
  _Float16* wu1f  = (_Float16*)alloc(1536ull * 4096 * 2);    // [W1;U1] B-fragments, permuted cols
  _Float16* wu2f  = (_Float16*)alloc(2048ull * 4096 * 2);    // [W2;U2]
  _Float16* fc1wf = (_Float16*)alloc(1024ull * 512 * 2);     // fc1_w B-fragments
  float* b1p      = (float*)alloc(4096 * 4);
  float* b2p      = (float*)alloc(4096 * 4);
  _Float16* ys1   = (_Float16*)alloc(257ull * 65536 * 2);    // h1 ring: [0]=h0, [t+1]=h1_t
  _Float16* ys2   = (_Float16*)alloc(257ull * 65536 * 2);    // h2 ring
  float* cbuf     = (float*)alloc(65536 * 4);                // cell state, [b][hcol] fp32
  float* Y1       = (float*)alloc(8388608ull * 4);           // FC1 out, [b][u][j] fp32
  float* part     = (float*)alloc(256ull * 64 * 36 * 4);     // FC2 partials
  int* bar        = (int*)alloc(512 * 4);                    // barrier state
  (void)in_sizes; (void)n_in; (void)out_size; (void)ws_size;

  prep_x_kernel<<<8388608 / 256, 256, 0, stream>>>(x, xh, 8388608);
  swizzle_b_kernel<<<(256 * 48 * 64) / 256, 256, 0, stream>>>(W1, U1, 512, 1536, 4096, 4096, 1, wu1f);
  swizzle_b_kernel<<<(256 * 64 * 64) / 256, 256, 0, stream>>>(W2, U2, 1024, 2048, 4096, 4096, 1, wu2f);
  swizzle_b_kernel<<<(32 * 32 * 64) / 256, 256, 0, stream>>>(fc1w, fc1w, 1024, 1024, 512, 512, 0, fc1wf);
  prep_small_kernel<<<256, 256, 0, stream>>>(b1, b2, h0, c0, b1p, b2p, ys1, cbuf, bar);

  // Layer 1: x part from xh ([b][t][d]: t-stride 512, b-stride 131072), 16 x-kblks
  lstm_layer_kernel<<<dim3(NB), dim3(NT), 0, stream>>>(
      xh, (size_t)512, (size_t)131072, 16, ys1, ys1, wu1f, b1p, cbuf, bar);
  // Layer 2: x part = ys1[t+1] (h1_t); h init = ys1[256] (h1 final); c continues in cbuf (c1 final)
  lstm_layer_kernel<<<dim3(NB), dim3(NT), 0, stream>>>(
      ys1 + 65536, (size_t)65536, (size_t)1024, 32, ys2, ys1 + (size_t)256 * 65536, wu2f, b2p, cbuf, bar);

  fc1_gemm_kernel<<<2048, 256, 0, stream>>>(ys2, fc1wf, fc1b, Y1);
  fc2_partial_kernel<<<256, 256, 0, stream>>>(Y1, fc2w, part);
  fc_final_kernel<<<1, 384, 0, stream>>>(part, fc2b, fc3w, fc3b, fc4w, fc4b, out);
}

// Round 2
// 11801.690 us; speedup vs baseline: 1.2268x; 1.2268x over previous
//
#include <hip/hip_runtime.h>

// ComplexModel: 2-layer LSTM (B=64,T=256,D=512,H=1024) + FC head, MI355X gfx950.
// R2: latency attack. Grid = 2 mb x 128 nb; block owns 32 batches x 8 hcols.
//  - h stored tiled [t][cg=col/8][b][col%8]: every 128B line has ONE owner block
//    (kills cross-XCD false sharing); consumer A-octet is one 16B load.
//  - c lives in registers (1 cell/thread), layer1->2 handoff via cfin buffer.
//  - barrier: 16x16 tree with 16-line generation broadcast (monotonic target t+1).
//  - x-part gates for step t+1 computed between barrier arrive and poll (overlap).

#define NT 256

typedef _Float16 f16x8 __attribute__((ext_vector_type(8)));
typedef float f32x4 __attribute__((ext_vector_type(4)));

__device__ __forceinline__ float sigm(float x)   { return 1.0f / (1.0f + __expf(-x)); }
__device__ __forceinline__ float tanh_f(float x) { return 1.0f - 2.0f / (__expf(2.0f * x) + 1.0f); }

// ---------------- prep kernels ----------------

// x [b][t][d] fp32 -> xh tiled f16: xh[t][dg=d/8][b][d%8]
__global__ void prep_x_kernel(const float* __restrict__ x, _Float16* __restrict__ xh) {
  int id = blockIdx.x * blockDim.x + threadIdx.x;   // 64*256*512
  int j = id & 7, b = (id >> 3) & 63, cg = (id >> 9) & 63, t = id >> 15;
  xh[id] = (_Float16)x[((size_t)b * 256 + t) * 512 + cg * 8 + j];
}

// Build MFMA B-fragment layout: dst[((nt*(K/32)+kb)*64 + lane)*8 + j] =
//   src[k = kb*32 + (lane>>4)*8 + j][col = perm(nt*16 + (lane&15))]
__global__ void swizzle_b_kernel(const float* __restrict__ src0, const float* __restrict__ src1,
                                 int k0, int K, int N, int srcStride, int permute,
                                 _Float16* __restrict__ dst) {
  int id = blockIdx.x * blockDim.x + threadIdx.x;
  int total = (N / 16) * (K / 32) * 64;
  if (id >= total) return;
  int lane = id & 63;
  int kb = (id >> 6) % (K / 32);
  int nt = id / ((K / 32) * 64);
  int kbase = kb * 32 + ((lane >> 4) << 3);
  int pc = nt * 16 + (lane & 15);
  int oc = permute ? ((pc & 3) * 1024 + (pc >> 2)) : pc;   // pc = 4*hcol + gate
  f16x8 v;
  #pragma unroll
  for (int j = 0; j < 8; ++j) {
    int k = kbase + j;
    float f = (k < k0) ? src0[(size_t)k * srcStride + oc]
                       : src1[(size_t)(k - k0) * srcStride + oc];
    v[j] = (_Float16)f;
  }
  ((f16x8*)dst)[id] = v;
}

__global__ void prep_small_kernel(const float* __restrict__ b1, const float* __restrict__ b2,
                                  const float* __restrict__ h0,
                                  float* __restrict__ b1p, float* __restrict__ b2p,
                                  _Float16* __restrict__ ys1_0, int* __restrict__ bar) {
  int i = blockIdx.x * blockDim.x + threadIdx.x;
  if (i < 4096) {
    int oc = (i & 3) * 1024 + (i >> 2);
    b1p[i] = b1[oc];
    b2p[i] = b2[oc];
  }
  if (i < 65536) {  // h0 [b][1024] -> tiled [cg][b][8]
    int j = i & 7, b = (i >> 3) & 63, cg = i >> 9;
    ys1_0[i] = (_Float16)h0[b * 1024 + cg * 8 + j];
  }
  if (i < 8192) bar[i] = 0;
}

// ---------------- persistent LSTM layer ----------------
// Grid 256 = mb(2) x nb(128). Block owns batches [32mb,32mb+32) x hcols [8nb,8nb+8)
// = permuted gate cols [32nb,32nb+32) = n-tiles {2nb, 2nb+1}. Waves: wm=w&1 (m-tile),
// wn=w>>1 (n-tile). h layout per t: [cg=col/8][b][col%8] (65536/32768 f16 per slot).
// Barrier: group g=blk>>4 (16 groups of 16); counters bar[g*64]; root bar[1024];
// generation broadcast bar[2048+g*64], monotonic value t+1.
__launch_bounds__(NT, 1)
__global__ void lstm_layer_kernel(const _Float16* __restrict__ xsrc, size_t xts, int kxb,
                                  _Float16* hseq, const _Float16* __restrict__ hinit,
                                  const _Float16* __restrict__ bfrag, const float* __restrict__ biasp,
                                  const float* __restrict__ cin, float* __restrict__ cout,
                                  int* bar) {
  __shared__ _Float16 Bs[2 * 32 * 64 * 8];   // 64 KB: U-part B fragments, 2 n-tiles
  __shared__ float gt[32 * 36];              // gate tile [b_local][pc_local], stride 36
  const int tid = threadIdx.x;
  const int lane = tid & 63;
  const int w = tid >> 6;
  const int wm = w & 1, wn = w >> 1;
  const int blk = blockIdx.x;
  const int mb = blk & 1, nb = blk >> 1;
  const int g = blk >> 4;
  const int KB = kxb + 32;
  const int ntg = 2 * nb + wn;

  {  // stage U-part B-fragments for the block's two n-tiles
    #pragma unroll
    for (int h = 0; h < 2; ++h) {
      const uint4* s = (const uint4*)bfrag + (size_t)((2 * nb + h) * KB + kxb) * 64;
      uint4* d = (uint4*)Bs + h * 2048;
      for (int i = tid; i < 2048; i += NT) d[i] = s[i];
    }
  }

  const f16x8* Bxg = (const f16x8*)bfrag;
  const f16x8* Bv  = (const f16x8*)Bs;
  const int q = lane >> 4;
  const int brow = mb * 32 + wm * 16 + (lane & 15);   // global batch this lane supplies (A)
  const int bl = tid >> 3, cl = tid & 7;              // cell-update: batch/col local
  const float bias = biasp[ntg * 16 + (lane & 15)];
  float cc = cin[(size_t)(mb * 32 + bl) * 1024 + 8 * nb + cl];  // register-resident cell state
  __syncthreads();

  // prologue: x-part of step 0 (h-independent)
  f32x4 acc = {bias, bias, bias, bias};
  {
    const f16x8* ax = (const f16x8*)xsrc;
    #pragma unroll 8
    for (int kb = 0; kb < kxb; ++kb)
      acc = __builtin_amdgcn_mfma_f32_16x16x32_f16(ax[(kb * 4 + q) * 64 + brow],
                                                   Bxg[(ntg * KB + kb) * 64 + lane], acc, 0, 0, 0);
  }

  for (int t = 0; t < 256; ++t) {
    // h-part (recurrent): h_t available (t==0: hinit, else released by barrier t)
    const f16x8* ah = (const f16x8*)((t == 0) ? hinit : (hseq + (size_t)t * 65536));
    #pragma unroll 8
    for (int kb = 0; kb < 32; ++kb)
      acc = __builtin_amdgcn_mfma_f32_16x16x32_f16(ah[(kb * 4 + q) * 64 + brow],
                                                   Bv[(wn * 32 + kb) * 64 + lane], acc, 0, 0, 0);

    // C layout: col=lane&15, row=(lane>>4)*4+r -> park in LDS as [b_local][pc_local]
    #pragma unroll
    for (int r = 0; r < 4; ++r)
      gt[(wm * 16 + q * 4 + r) * 36 + wn * 16 + (lane & 15)] = acc[r];
    __syncthreads();
    float4 gv = *(float4*)&gt[bl * 36 + cl * 4];       // i,f,g,o for this thread's cell
    cc = sigm(gv.y) * cc + sigm(gv.x) * tanh_f(gv.z);
    float hn = sigm(gv.w) * tanh_f(cc);
    // single-owner contiguous store: block writes 512B (4 lines), one 128B line per wave
    hseq[(size_t)(t + 1) * 65536 + nb * 512 + (mb * 32 + bl) * 8 + cl] = (_Float16)hn;
    __syncthreads();                                    // drain stores + finish gt reads

    if (t < 255) {
      if (tid == 0) {  // arrive
        __threadfence();
        int old = __hip_atomic_fetch_add(&bar[g * 64], 1, __ATOMIC_ACQ_REL, __HIP_MEMORY_SCOPE_AGENT);
        if (old == 15) {
          int r = __hip_atomic_fetch_add(&bar[1024], 1, __ATOMIC_ACQ_REL, __HIP_MEMORY_SCOPE_AGENT);
          if (r == 15) {  // last group leader: reset, then publish generation t+1
            #pragma unroll
            for (int i = 0; i < 16; ++i)
              __hip_atomic_store(&bar[i * 64], 0, __ATOMIC_RELAXED, __HIP_MEMORY_SCOPE_AGENT);
            __hip_atomic_store(&bar[1024], 0, __ATOMIC_RELAXED, __HIP_MEMORY_SCOPE_AGENT);
            #pragma unroll
            for (int i = 0; i < 16; ++i)
              __hip_atomic_store(&bar[2048 + i * 64], t + 1, __ATOMIC_RELEASE, __HIP_MEMORY_SCOPE_AGENT);
          }
        }
      }
      // overlap the barrier wait with the h-independent x-part of step t+1
      f32x4 a2 = {bias, bias, bias, bias};
      {
        const f16x8* ax = (const f16x8*)(xsrc + (size_t)(t + 1) * xts);
        #pragma unroll 8
        for (int kb = 0; kb < kxb; ++kb)
          a2 = __builtin_amdgcn_mfma_f32_16x16x32_f16(ax[(kb * 4 + q) * 64 + brow],
                                                      Bxg[(ntg * KB + kb) * 64 + lane], a2, 0, 0, 0);
      }
      if (tid == 0) {  // poll own group's generation line (16 pollers/line)
        while (__hip_atomic_load(&bar[2048 + g * 64], __ATOMIC_RELAXED, __HIP_MEMORY_SCOPE_AGENT) < t + 1)
          __builtin_amdgcn_s_sleep(2);
        (void)__hip_atomic_load(&bar[2048 + g * 64], __ATOMIC_ACQUIRE, __HIP_MEMORY_SCOPE_AGENT);
      }
      __syncthreads();
      acc = a2;
    }
  }
  if (cout) cout[(size_t)(mb * 32 + bl) * 1024 + 8 * nb + cl] = cc;
}

// ---------------- FC head ----------------

// Y1[b][u][j] = ys2[u+1][b][:] @ fc1_w[:, j] + fc1_b[j]   (16384x1024 @ 1024x512)
__launch_bounds__(256, 1)
__global__ void fc1_gemm_kernel(const _Float16* __restrict__ ys2, const _Float16* __restrict__ wfrag,
                                const float* __restrict__ fc1b, float* __restrict__ Y1) {
  const int mb = blockIdx.x >> 3;
  const int nb = blockIdx.x & 7;
  const int tid = threadIdx.x;
  const int lane = tid & 63;
  const int w = tid >> 6;
  const int q = lane >> 4;
  const int R0 = mb * 64 + w * 16;
  const int arow = R0 + (lane & 15);           // row = u*64 + b
  const int u = arow >> 6;
  const int b = arow & 63;
  const f16x8* A = (const f16x8*)(ys2 + (size_t)(u + 1) * 65536);  // tiled [cg][b][8]
  const f16x8* W = (const f16x8*)wfrag;
  f32x4 acc[4];
  #pragma unroll
  for (int n = 0; n < 4; ++n) acc[n] = (f32x4){0.f, 0.f, 0.f, 0.f};
  #pragma unroll 4
  for (int kb = 0; kb < 32; ++kb) {
    f16x8 a = A[(kb * 4 + q) * 64 + b];
    #pragma unroll
    for (int n = 0; n < 4; ++n)
      acc[n] = __builtin_amdgcn_mfma_f32_16x16x32_f16(a, W[(((nb * 4 + n) * 32) + kb) * 64 + lane],
                                                      acc[n], 0, 0, 0);
  }
  const int rb = R0 + (q << 2);
  #pragma unroll
  for (int n = 0; n < 4; ++n) {
    int col = nb * 64 + n * 16 + (lane & 15);
    float bias = fc1b[col];
    #pragma unroll
    for (int r = 0; r < 4; ++r) {
      int R = rb + r;
      Y1[((size_t)(R & 63) * 256 + (R >> 6)) * 512 + col] = acc[n][r] + bias;
    }
  }
}

// FC2 partial reduction: 256 K-chunks of 512; part[kc][b][36]
__global__ void fc2_partial_kernel(const float* __restrict__ Y1, const float* __restrict__ fc2w,
                                   float* __restrict__ part) {
  int kc = blockIdx.x;
  int tid = threadIdx.x;
  int b = tid >> 2, qq = tid & 3;
  const float* y = Y1 + (size_t)b * 131072 + (size_t)kc * 512;
  const float* wbase = fc2w + (size_t)kc * 512 * 36 + qq * 9;
  float acc[9];
  #pragma unroll
  for (int j = 0; j < 9; ++j) acc[j] = 0.f;
  for (int k = 0; k < 512; ++k) {
    float yv = y[k];
    const float* wr = wbase + (size_t)k * 36;
    #pragma unroll
    for (int j = 0; j < 9; ++j) acc[j] = fmaf(yv, wr[j], acc[j]);
  }
  float* o = part + ((size_t)kc * 64 + b) * 36 + qq * 9;
  #pragma unroll
  for (int j = 0; j < 9; ++j) o[j] = acc[j];
}

__global__ void fc_final_kernel(const float* __restrict__ part, const float* __restrict__ fc2b,
                                const float* __restrict__ fc3w, const float* __restrict__ fc3b,
                                const float* __restrict__ fc4w, const float* __restrict__ fc4b,
                                float* __restrict__ out) {
  __shared__ float z2[64 * 36];
  __shared__ float z3[64 * 6];
  int tid = threadIdx.x;  // 384
  for (int idx = tid; idx < 64 * 36; idx += 384) {
    int b = idx / 36, m = idx % 36;
    float s = fc2b[m];
    for (int kc = 0; kc < 256; ++kc) s += part[((size_t)kc * 64 + b) * 36 + m];
    z2[idx] = s;
  }
  __syncthreads();
  {
    int b = tid / 6, n = tid % 6;
    float s = fc3b[n];
    #pragma unroll 4
    for (int m = 0; m < 36; ++m) s += z2[b * 36 + m] * fc3w[m * 6 + n];
    z3[tid] = s;
  }
  __syncthreads();
  {
    int b = tid / 6, n = tid % 6;
    float s = fc4b[n];
    #pragma unroll
    for (int m = 0; m < 6; ++m) s += z3[b * 6 + m] * fc4w[m * 6 + n];
    out[tid] = fmaxf(s, 0.0f);
  }
}

// ---------------- host ----------------

extern "C" void kernel_launch(void* const* d_in, const int* in_sizes, int n_in,
                              void* d_out, int out_size, void* d_ws, size_t ws_size,
                              hipStream_t stream) {
  const float* x    = (const float*)d_in[0];
  const float* h0   = (const float*)d_in[1];
  const float* c0   = (const float*)d_in[2];
  const float* W1   = (const float*)d_in[3];
  const float* U1   = (const float*)d_in[4];
  const float* b1   = (const float*)d_in[5];
  const float* W2   = (const float*)d_in[6];
  const float* U2   = (const float*)d_in[7];
  const float* b2   = (const float*)d_in[8];
  const float* fc1w = (const float*)d_in[9];
  const float* fc1b = (const float*)d_in[10];
  const float* fc2w = (const float*)d_in[11];
  const float* fc2b = (const float*)d_in[12];
  const float* fc3w = (const float*)d_in[13];
  const float* fc3b = (const float*)d_in[14];
  const float* fc4w = (const float*)d_in[15];
  const float* fc4b = (const float*)d_in[16];
  float* out = (float*)d_out;

  char* p = (char*)d_ws;
  auto alloc = [&](size_t bytes) { char* r = p; p += (bytes + 255) & ~(size_t)255; return r; };
  _Float16* xh    = (_Float16*)alloc(8388608ull * 2);        // x tiled f16 [t][dg][b][8]
  _Float16* wu1f  = (_Float16*)alloc(1536ull * 4096 * 2);    // [W1;U1] B-fragments, permuted cols
  _Float16* wu2f  = (_Float16*)alloc(2048ull * 4096 * 2);    // [W2;U2]
  _Float16* fc1wf = (_Float16*)alloc(1024ull * 512 * 2);     // fc1_w B-fragments
  float* b1p      = (float*)alloc(4096 * 4);
  float* b2p      = (float*)alloc(4096 * 4);
  _Float16* ys1   = (_Float16*)alloc(257ull * 65536 * 2);    // h1 slots, tiled: [0]=h0, [t+1]=h1_t
  _Float16* ys2   = (_Float16*)alloc(257ull * 65536 * 2);    // h2 slots, tiled
  float* cfin     = (float*)alloc(65536 * 4);                // c1 final [b][h] fp32
  float* Y1       = (float*)alloc(8388608ull * 4);           // FC1 out, [b][u][j] fp32
  float* part     = (float*)alloc(256ull * 64 * 36 * 4);     // FC2 partials
  int* bar        = (int*)alloc(8192 * 4);                   // 2 barrier regions (4096 ints each)
  (void)in_sizes; (void)n_in; (void)out_size; (void)ws_size;

  prep_x_kernel<<<8388608 / 256, 256, 0, stream>>>(x, xh);
  swizzle_b_kernel<<<(256 * 48 * 64) / 256, 256, 0, stream>>>(W1, U1, 512, 1536, 4096, 4096, 1, wu1f);
  swizzle_b_kernel<<<(256 * 64 * 64) / 256, 256, 0, stream>>>(W2, U2, 1024, 2048, 4096, 4096, 1, wu2f);
  swizzle_b_kernel<<<(32 * 32 * 64) / 256, 256, 0, stream>>>(fc1w, fc1w, 1024, 1024, 512, 512, 0, fc1wf);
  prep_small_kernel<<<256, 256, 0, stream>>>(b1, b2, h0, b1p, b2p, ys1, bar);

  // Layer 1: x part from xh (t-stride 32768 f16), 16 x-kblks; h slot0 = h0; c from c0 -> cfin
  lstm_layer_kernel<<<256, NT, 0, stream>>>(
      xh, (size_t)32768, 16, ys1, ys1, wu1f, b1p, c0, cfin, bar);
  // Layer 2: x part = ys1 slots 1..256 (t-stride 65536), 32 x-kblks; h init = ys1 slot 256; c from cfin
  lstm_layer_kernel<<<256, NT, 0, stream>>>(
      ys1 + 65536, (size_t)65536, 32, ys2, ys1 + (size_t)256 * 65536, wu2f, b2p, cfin, nullptr, bar + 4096);

  fc1_gemm_kernel<<<2048, 256, 0, stream>>>(ys2, fc1wf, fc1b, Y1);
  fc2_partial_kernel<<<256, 256, 0, stream>>>(Y1, fc2w, part);
  fc_final_kernel<<<1, 384, 0, stream>>>(part, fc2b, fc3w, fc3b, fc4w, fc4b, out);
}

// Round 3
// 5944.392 us; speedup vs baseline: 2.4356x; 1.9853x over previous
//
#include <hip/hip_runtime.h>

// ComplexModel: 2-layer LSTM (B=64,T=256,D=512,H=1024) + FC head, MI355X gfx950.
// R3: fence-free recurrence. No __threadfence / acquire in the step loop (those
// emitted buffer_wbl2/buffer_inv -> full L2 flush per step per block, FETCH 1GB).
//  - h communicated via agent-scope RELAXED atomic stores/loads (sc1: write-through /
//    cache-bypass at the coherence point); weights & x stay L2-resident.
//  - only wave 0 stores h (LDS-staged, 64x 8B sc1 stores); s_waitcnt(0) in wave 0
//    orders stores before the arrival atomic.
//  - monotonic barrier counters (no resets): group g target 16t+15, root 16t+15,
//    16 generation broadcast lines publish t+1.
//  - x-part gates of step t+1 computed in the barrier-wait shadow.

#define NT 256

typedef _Float16 f16x8 __attribute__((ext_vector_type(8)));
typedef float f32x4 __attribute__((ext_vector_type(4)));
typedef unsigned long long u64;

__device__ __forceinline__ float sigm(float x)   { return 1.0f / (1.0f + __expf(-x)); }
__device__ __forceinline__ float tanh_f(float x) { return 1.0f - 2.0f / (__expf(2.0f * x) + 1.0f); }

// 16B MFMA A-fragment load that bypasses stale caches (agent-coherent, relaxed)
__device__ __forceinline__ f16x8 load_frag_coh(const _Float16* p) {
  union { u64 u[2]; f16x8 v; } c;
  c.u[0] = __hip_atomic_load((const u64*)p,     __ATOMIC_RELAXED, __HIP_MEMORY_SCOPE_AGENT);
  c.u[1] = __hip_atomic_load((const u64*)p + 1, __ATOMIC_RELAXED, __HIP_MEMORY_SCOPE_AGENT);
  return c.v;
}

// ---------------- prep kernels ----------------

// x [b][t][d] fp32 -> xh tiled f16: xh[t][dg=d/8][b][d%8]
__global__ void prep_x_kernel(const float* __restrict__ x, _Float16* __restrict__ xh) {
  int id = blockIdx.x * blockDim.x + threadIdx.x;   // 64*256*512
  int j = id & 7, b = (id >> 3) & 63, cg = (id >> 9) & 63, t = id >> 15;
  xh[id] = (_Float16)x[((size_t)b * 256 + t) * 512 + cg * 8 + j];
}

// Build MFMA B-fragment layout: dst[((nt*(K/32)+kb)*64 + lane)*8 + j] =
//   src[k = kb*32 + (lane>>4)*8 + j][col = perm(nt*16 + (lane&15))]
__global__ void swizzle_b_kernel(const float* __restrict__ src0, const float* __restrict__ src1,
                                 int k0, int K, int N, int srcStride, int permute,
                                 _Float16* __restrict__ dst) {
  int id = blockIdx.x * blockDim.x + threadIdx.x;
  int total = (N / 16) * (K / 32) * 64;
  if (id >= total) return;
  int lane = id & 63;
  int kb = (id >> 6) % (K / 32);
  int nt = id / ((K / 32) * 64);
  int kbase = kb * 32 + ((lane >> 4) << 3);
  int pc = nt * 16 + (lane & 15);
  int oc = permute ? ((pc & 3) * 1024 + (pc >> 2)) : pc;   // pc = 4*hcol + gate
  f16x8 v;
  #pragma unroll
  for (int j = 0; j < 8; ++j) {
    int k = kbase + j;
    float f = (k < k0) ? src0[(size_t)k * srcStride + oc]
                       : src1[(size_t)(k - k0) * srcStride + oc];
    v[j] = (_Float16)f;
  }
  ((f16x8*)dst)[id] = v;
}

__global__ void prep_small_kernel(const float* __restrict__ b1, const float* __restrict__ b2,
                                  const float* __restrict__ h0,
                                  float* __restrict__ b1p, float* __restrict__ b2p,
                                  _Float16* __restrict__ ys1_0, int* __restrict__ bar) {
  int i = blockIdx.x * blockDim.x + threadIdx.x;
  if (i < 4096) {
    int oc = (i & 3) * 1024 + (i >> 2);
    b1p[i] = b1[oc];
    b2p[i] = b2[oc];
  }
  if (i < 65536) {  // h0 [b][1024] -> tiled [cg][b][8]
    int j = i & 7, b = (i >> 3) & 63, cg = i >> 9;
    ys1_0[i] = (_Float16)h0[b * 1024 + cg * 8 + j];
  }
  if (i < 8192) bar[i] = 0;
}

// ---------------- persistent LSTM layer ----------------
// Grid 256 = mb(2) x nb(128). Block owns batches [32mb,32mb+32) x hcols [8nb,8nb+8)
// = permuted gate cols [32nb,32nb+32) = n-tiles {2nb,2nb+1}. Waves: wm=w&1 (m-tile),
// wn=w>>1 (n-tile). h slot layout: [cg=col/8][b][col%8].
// Barrier (monotonic): bar[g*32] g<16 group counters; bar[512] root; bar[1024+g*32] gen.
__launch_bounds__(NT, 1)
__global__ void lstm_layer_kernel(const _Float16* __restrict__ xsrc, size_t xts, int kxb,
                                  _Float16* hseq, const _Float16* __restrict__ hinit,
                                  const _Float16* __restrict__ bfrag, const float* __restrict__ biasp,
                                  const float* __restrict__ cin, float* __restrict__ cout,
                                  int* bar) {
  __shared__ _Float16 Bs[2 * 32 * 64 * 8];   // 64 KB: U-part B fragments, 2 n-tiles
  __shared__ float gt[32 * 36];              // gate tile [b_local][pc_local]
  __shared__ _Float16 hlds[256];             // staged h outputs (block-linear = tid)
  const int tid = threadIdx.x;
  const int lane = tid & 63;
  const int w = tid >> 6;
  const int wm = w & 1, wn = w >> 1;
  const int blk = blockIdx.x;
  const int mb = blk & 1, nb = blk >> 1;
  const int g = blk >> 4;
  const int KB = kxb + 32;
  const int ntg = 2 * nb + wn;

  {  // stage U-part B-fragments for the block's two n-tiles
    #pragma unroll
    for (int h = 0; h < 2; ++h) {
      const uint4* s = (const uint4*)bfrag + (size_t)((2 * nb + h) * KB + kxb) * 64;
      uint4* d = (uint4*)Bs + h * 2048;
      for (int i = tid; i < 2048; i += NT) d[i] = s[i];
    }
  }

  const f16x8* Bxg = (const f16x8*)bfrag;
  const f16x8* Bv  = (const f16x8*)Bs;
  const int q = lane >> 4;
  const int brow = mb * 32 + wm * 16 + (lane & 15);   // global batch this lane supplies (A)
  const int bl = tid >> 3, cl = tid & 7;              // cell-update: batch/col local
  const float bias = biasp[ntg * 16 + (lane & 15)];
  float cc = cin[(size_t)(mb * 32 + bl) * 1024 + 8 * nb + cl];  // register-resident cell
  const u64 hstBase = (u64)(nb * 128 + mb * 64);      // u64 index of block's h span
  __syncthreads();

  // prologue: x-part of step 0 (h-independent)
  f32x4 acc = {bias, bias, bias, bias};
  {
    const f16x8* ax = (const f16x8*)xsrc;
    #pragma unroll 8
    for (int kb = 0; kb < kxb; ++kb)
      acc = __builtin_amdgcn_mfma_f32_16x16x32_f16(ax[(kb * 4 + q) * 64 + brow],
                                                   Bxg[(ntg * KB + kb) * 64 + lane], acc, 0, 0, 0);
  }

  for (int t = 0; t < 256; ++t) {
    // h-part (recurrent): coherent loads (remote blocks wrote via sc1)
    const _Float16* hb = (t == 0) ? hinit : (hseq + (size_t)t * 65536);
    #pragma unroll 8
    for (int kb = 0; kb < 32; ++kb) {
      f16x8 a = load_frag_coh(hb + (((kb * 4 + q) << 6) + brow) * 8);
      acc = __builtin_amdgcn_mfma_f32_16x16x32_f16(a, Bv[(wn * 32 + kb) * 64 + lane], acc, 0, 0, 0);
    }

    // C layout: col=lane&15, row=(lane>>4)*4+r -> park in LDS as [b_local][pc_local]
    #pragma unroll
    for (int r = 0; r < 4; ++r)
      gt[(wm * 16 + q * 4 + r) * 36 + wn * 16 + (lane & 15)] = acc[r];
    __syncthreads();
    float4 gv = *(float4*)&gt[bl * 36 + cl * 4];       // i,f,g,o for this thread's cell
    cc = sigm(gv.y) * cc + sigm(gv.x) * tanh_f(gv.z);
    float hn = sigm(gv.w) * tanh_f(cc);
    hlds[tid] = (_Float16)hn;
    __syncthreads();

    // wave 0: publish the block's 512B h span via agent-coherent stores (sc1)
    if (w == 0) {
      u64 v = ((const u64*)hlds)[lane];
      __hip_atomic_store((u64*)(hseq + (size_t)(t + 1) * 65536) + hstBase + lane, v,
                         __ATOMIC_RELAXED, __HIP_MEMORY_SCOPE_AGENT);
    }

    if (t < 255) {
      if (tid == 0) {  // arrive (stores of wave 0 drained first; no cache fences)
        __builtin_amdgcn_s_waitcnt(0);
        __atomic_signal_fence(__ATOMIC_SEQ_CST);
        int tgt = (t << 4) + 15;
        int old = __hip_atomic_fetch_add(&bar[g * 32], 1, __ATOMIC_RELAXED, __HIP_MEMORY_SCOPE_AGENT);
        if (old == tgt) {
          int r = __hip_atomic_fetch_add(&bar[512], 1, __ATOMIC_RELAXED, __HIP_MEMORY_SCOPE_AGENT);
          if (r == tgt) {
            #pragma unroll
            for (int i = 0; i < 16; ++i)
              __hip_atomic_store(&bar[1024 + i * 32], t + 1, __ATOMIC_RELAXED, __HIP_MEMORY_SCOPE_AGENT);
          }
        }
      }
      // overlap the barrier wait with the h-independent x-part of step t+1
      f32x4 a2 = {bias, bias, bias, bias};
      {
        const f16x8* ax = (const f16x8*)(xsrc + (size_t)(t + 1) * xts);
        #pragma unroll 8
        for (int kb = 0; kb < kxb; ++kb)
          a2 = __builtin_amdgcn_mfma_f32_16x16x32_f16(ax[(kb * 4 + q) * 64 + brow],
                                                      Bxg[(ntg * KB + kb) * 64 + lane], a2, 0, 0, 0);
      }
      if (tid == 0) {  // poll own group's generation line
        while (__hip_atomic_load(&bar[1024 + g * 32], __ATOMIC_RELAXED, __HIP_MEMORY_SCOPE_AGENT) < t + 1)
          __builtin_amdgcn_s_sleep(2);
        __atomic_signal_fence(__ATOMIC_SEQ_CST);
      }
      __syncthreads();
      acc = a2;
    }
  }
  if (cout) cout[(size_t)(mb * 32 + bl) * 1024 + 8 * nb + cl] = cc;
}

// ---------------- FC head ----------------

// Y1[b][u][j] = ys2[u+1][b][:] @ fc1_w[:, j] + fc1_b[j]   (16384x1024 @ 1024x512)
__launch_bounds__(256, 1)
__global__ void fc1_gemm_kernel(const _Float16* __restrict__ ys2, const _Float16* __restrict__ wfrag,
                                const float* __restrict__ fc1b, float* __restrict__ Y1) {
  const int mb = blockIdx.x >> 3;
  const int nb = blockIdx.x & 7;
  const int tid = threadIdx.x;
  const int lane = tid & 63;
  const int w = tid >> 6;
  const int q = lane >> 4;
  const int R0 = mb * 64 + w * 16;
  const int arow = R0 + (lane & 15);           // row = u*64 + b
  const int u = arow >> 6;
  const int b = arow & 63;
  const f16x8* A = (const f16x8*)(ys2 + (size_t)(u + 1) * 65536);  // tiled [cg][b][8]
  const f16x8* W = (const f16x8*)wfrag;
  f32x4 acc[4];
  #pragma unroll
  for (int n = 0; n < 4; ++n) acc[n] = (f32x4){0.f, 0.f, 0.f, 0.f};
  #pragma unroll 4
  for (int kb = 0; kb < 32; ++kb) {
    f16x8 a = A[(kb * 4 + q) * 64 + b];
    #pragma unroll
    for (int n = 0; n < 4; ++n)
      acc[n] = __builtin_amdgcn_mfma_f32_16x16x32_f16(a, W[(((nb * 4 + n) * 32) + kb) * 64 + lane],
                                                      acc[n], 0, 0, 0);
  }
  const int rb = R0 + (q << 2);
  #pragma unroll
  for (int n = 0; n < 4; ++n) {
    int col = nb * 64 + n * 16 + (lane & 15);
    float bias = fc1b[col];
    #pragma unroll
    for (int r = 0; r < 4; ++r) {
      int R = rb + r;
      Y1[((size_t)(R & 63) * 256 + (R >> 6)) * 512 + col] = acc[n][r] + bias;
    }
  }
}

// FC2 partial reduction: 256 K-chunks of 512; part[kc][b][36]
__global__ void fc2_partial_kernel(const float* __restrict__ Y1, const float* __restrict__ fc2w,
                                   float* __restrict__ part) {
  int kc = blockIdx.x;
  int tid = threadIdx.x;
  int b = tid >> 2, qq = tid & 3;
  const float* y = Y1 + (size_t)b * 131072 + (size_t)kc * 512;
  const float* wbase = fc2w + (size_t)kc * 512 * 36 + qq * 9;
  float acc[9];
  #pragma unroll
  for (int j = 0; j < 9; ++j) acc[j] = 0.f;
  for (int k = 0; k < 512; ++k) {
    float yv = y[k];
    const float* wr = wbase + (size_t)k * 36;
    #pragma unroll
    for (int j = 0; j < 9; ++j) acc[j] = fmaf(yv, wr[j], acc[j]);
  }
  float* o = part + ((size_t)kc * 64 + b) * 36 + qq * 9;
  #pragma unroll
  for (int j = 0; j < 9; ++j) o[j] = acc[j];
}

__global__ void fc_final_kernel(const float* __restrict__ part, const float* __restrict__ fc2b,
                                const float* __restrict__ fc3w, const float* __restrict__ fc3b,
                                const float* __restrict__ fc4w, const float* __restrict__ fc4b,
                                float* __restrict__ out) {
  __shared__ float z2[64 * 36];
  __shared__ float z3[64 * 6];
  int tid = threadIdx.x;  // 384
  for (int idx = tid; idx < 64 * 36; idx += 384) {
    int b = idx / 36, m = idx % 36;
    float s = fc2b[m];
    for (int kc = 0; kc < 256; ++kc) s += part[((size_t)kc * 64 + b) * 36 + m];
    z2[idx] = s;
  }
  __syncthreads();
  {
    int b = tid / 6, n = tid % 6;
    float s = fc3b[n];
    #pragma unroll 4
    for (int m = 0; m < 36; ++m) s += z2[b * 36 + m] * fc3w[m * 6 + n];
    z3[tid] = s;
  }
  __syncthreads();
  {
    int b = tid / 6, n = tid % 6;
    float s = fc4b[n];
    #pragma unroll
    for (int m = 0; m < 6; ++m) s += z3[b * 6 + m] * fc4w[m * 6 + n];
    out[tid] = fmaxf(s, 0.0f);
  }
}

// ---------------- host ----------------

extern "C" void kernel_launch(void* const* d_in, const int* in_sizes, int n_in,
                              void* d_out, int out_size, void* d_ws, size_t ws_size,
                              hipStream_t stream) {
  const float* x    = (const float*)d_in[0];
  const float* h0   = (const float*)d_in[1];
  const float* c0   = (const float*)d_in[2];
  const float* W1   = (const float*)d_in[3];
  const float* U1   = (const float*)d_in[4];
  const float* b1   = (const float*)d_in[5];
  const float* W2   = (const float*)d_in[6];
  const float* U2   = (const float*)d_in[7];
  const float* b2   = (const float*)d_in[8];
  const float* fc1w = (const float*)d_in[9];
  const float* fc1b = (const float*)d_in[10];
  const float* fc2w = (const float*)d_in[11];
  const float* fc2b = (const float*)d_in[12];
  const float* fc3w = (const float*)d_in[13];
  const float* fc3b = (const float*)d_in[14];
  const float* fc4w = (const float*)d_in[15];
  const float* fc4b = (const float*)d_in[16];
  float* out = (float*)d_out;

  char* p = (char*)d_ws;
  auto alloc = [&](size_t bytes) { char* r = p; p += (bytes + 255) & ~(size_t)255; return r; };
  _Float16* xh    = (_Float16*)alloc(8388608ull * 2);        // x tiled f16 [t][dg][b][8]
  _Float16* wu1f  = (_Float16*)alloc(1536ull * 4096 * 2);    // [W1;U1] B-fragments, permuted cols
  _Float16* wu2f  = (_Float16*)alloc(2048ull * 4096 * 2);    // [W2;U2]
  _Float16* fc1wf = (_Float16*)alloc(1024ull * 512 * 2);     // fc1_w B-fragments
  float* b1p      = (float*)alloc(4096 * 4);
  float* b2p      = (float*)alloc(4096 * 4);
  _Float16* ys1   = (_Float16*)alloc(257ull * 65536 * 2);    // h1 slots, tiled: [0]=h0, [t+1]=h1_t
  _Float16* ys2   = (_Float16*)alloc(257ull * 65536 * 2);    // h2 slots, tiled
  float* cfin     = (float*)alloc(65536 * 4);                // c1 final [b][h] fp32
  float* Y1       = (float*)alloc(8388608ull * 4);           // FC1 out, [b][u][j] fp32
  float* part     = (float*)alloc(256ull * 64 * 36 * 4);     // FC2 partials
  int* bar        = (int*)alloc(8192 * 4);                   // 2 barrier regions (2048 ints each)
  (void)in_sizes; (void)n_in; (void)out_size; (void)ws_size;

  prep_x_kernel<<<8388608 / 256, 256, 0, stream>>>(x, xh);
  swizzle_b_kernel<<<(256 * 48 * 64) / 256, 256, 0, stream>>>(W1, U1, 512, 1536, 4096, 4096, 1, wu1f);
  swizzle_b_kernel<<<(256 * 64 * 64) / 256, 256, 0, stream>>>(W2, U2, 1024, 2048, 4096, 4096, 1, wu2f);
  swizzle_b_kernel<<<(32 * 32 * 64) / 256, 256, 0, stream>>>(fc1w, fc1w, 1024, 1024, 512, 512, 0, fc1wf);
  prep_small_kernel<<<256, 256, 0, stream>>>(b1, b2, h0, b1p, b2p, ys1, bar);

  // Layer 1: x from xh (t-stride 32768 f16), 16 x-kblks; h slot0 = h0; c: c0 -> cfin
  lstm_layer_kernel<<<256, NT, 0, stream>>>(
      xh, (size_t)32768, 16, ys1, ys1, wu1f, b1p, c0, cfin, bar);
  // Layer 2: x = ys1 slots 1..256 (t-stride 65536), 32 x-kblks; h init = ys1 slot 256; c from cfin
  lstm_layer_kernel<<<256, NT, 0, stream>>>(
      ys1 + 65536, (size_t)65536, 32, ys2, ys1 + (size_t)256 * 65536, wu2f, b2p, cfin, nullptr, bar + 2048);

  fc1_gemm_kernel<<<2048, 256, 0, stream>>>(ys2, fc1wf, fc1b, Y1);
  fc2_partial_kernel<<<256, 256, 0, stream>>>(Y1, fc2w, part);
  fc_final_kernel<<<1, 384, 0, stream>>>(part, fc2b, fc3w, fc3b, fc4w, fc4b, out);
}

// Round 4
// 5882.166 us; speedup vs baseline: 2.4614x; 1.0106x over previous
//
#include <hip/hip_runtime.h>

// ComplexModel: 2-layer LSTM (B=64,T=256,D=512,H=1024) + FC head, MI355X gfx950.
// R4: minimal sync chain. The two mb halves are independent sync domains
// (block (mb,nb) only consumes h written by blocks (mb,*)). Per step:
//   producer wave0: h sc1 stores -> s_waitcnt(0) -> per-block flag := t+1 (sc1 relaxed)
//   consumers: every wave polls its half's 128 flags directly (64 lanes x 8B sc1)
// No atomic RMW tree, no generation broadcast, no __syncthreads after release.
// x-part gates of step t+1 computed in the publish->poll shadow.

#define NT 256

typedef _Float16 f16x8 __attribute__((ext_vector_type(8)));
typedef float f32x4 __attribute__((ext_vector_type(4)));
typedef unsigned long long u64;

__device__ __forceinline__ float sigm(float x)   { return 1.0f / (1.0f + __expf(-x)); }
__device__ __forceinline__ float tanh_f(float x) { return 1.0f - 2.0f / (__expf(2.0f * x) + 1.0f); }

// 16B MFMA A-fragment load that bypasses stale caches (agent-coherent, relaxed)
__device__ __forceinline__ f16x8 load_frag_coh(const _Float16* p) {
  union { u64 u[2]; f16x8 v; } c;
  c.u[0] = __hip_atomic_load((const u64*)p,     __ATOMIC_RELAXED, __HIP_MEMORY_SCOPE_AGENT);
  c.u[1] = __hip_atomic_load((const u64*)p + 1, __ATOMIC_RELAXED, __HIP_MEMORY_SCOPE_AGENT);
  return c.v;
}

// ---------------- prep kernels ----------------

// x [b][t][d] fp32 -> xh tiled f16: xh[t][dg=d/8][b][d%8]
__global__ void prep_x_kernel(const float* __restrict__ x, _Float16* __restrict__ xh) {
  int id = blockIdx.x * blockDim.x + threadIdx.x;   // 64*256*512
  int j = id & 7, b = (id >> 3) & 63, cg = (id >> 9) & 63, t = id >> 15;
  xh[id] = (_Float16)x[((size_t)b * 256 + t) * 512 + cg * 8 + j];
}

// Build MFMA B-fragment layout: dst[((nt*(K/32)+kb)*64 + lane)*8 + j] =
//   src[k = kb*32 + (lane>>4)*8 + j][col = perm(nt*16 + (lane&15))]
__global__ void swizzle_b_kernel(const float* __restrict__ src0, const float* __restrict__ src1,
                                 int k0, int K, int N, int srcStride, int permute,
                                 _Float16* __restrict__ dst) {
  int id = blockIdx.x * blockDim.x + threadIdx.x;
  int total = (N / 16) * (K / 32) * 64;
  if (id >= total) return;
  int lane = id & 63;
  int kb = (id >> 6) % (K / 32);
  int nt = id / ((K / 32) * 64);
  int kbase = kb * 32 + ((lane >> 4) << 3);
  int pc = nt * 16 + (lane & 15);
  int oc = permute ? ((pc & 3) * 1024 + (pc >> 2)) : pc;   // pc = 4*hcol + gate
  f16x8 v;
  #pragma unroll
  for (int j = 0; j < 8; ++j) {
    int k = kbase + j;
    float f = (k < k0) ? src0[(size_t)k * srcStride + oc]
                       : src1[(size_t)(k - k0) * srcStride + oc];
    v[j] = (_Float16)f;
  }
  ((f16x8*)dst)[id] = v;
}

__global__ void prep_small_kernel(const float* __restrict__ b1, const float* __restrict__ b2,
                                  const float* __restrict__ h0,
                                  float* __restrict__ b1p, float* __restrict__ b2p,
                                  _Float16* __restrict__ ys1_0, int* __restrict__ bar) {
  int i = blockIdx.x * blockDim.x + threadIdx.x;
  if (i < 4096) {
    int oc = (i & 3) * 1024 + (i >> 2);
    b1p[i] = b1[oc];
    b2p[i] = b2[oc];
  }
  if (i < 65536) {  // h0 [b][1024] -> tiled [cg][b][8]
    int j = i & 7, b = (i >> 3) & 63, cg = i >> 9;
    ys1_0[i] = (_Float16)h0[b * 1024 + cg * 8 + j];
  }
  if (i < 8192) bar[i] = 0;
}

// ---------------- persistent LSTM layer ----------------
// Grid 256 = mb(2) x nb(128). Block owns batches [32mb,32mb+32) x hcols [8nb,8nb+8)
// = permuted gate cols [32nb,32nb+32) = n-tiles {2nb,2nb+1}. 4 waves: wm=w&1 (m-tile),
// wn=w>>1 (n-tile). h slot layout: [cg=col/8][b][col%8].
// Sync: flags bar[mb*128 + nb] monotonic = last published step+1.
__launch_bounds__(NT, 1)
__global__ void lstm_layer_kernel(const _Float16* __restrict__ xsrc, size_t xts, int kxb,
                                  _Float16* hseq, const _Float16* __restrict__ hinit,
                                  const _Float16* __restrict__ bfrag, const float* __restrict__ biasp,
                                  const float* __restrict__ cin, float* __restrict__ cout,
                                  int* bar) {
  __shared__ _Float16 Bs[2 * 32 * 64 * 8];   // 64 KB: U-part B fragments, 2 n-tiles
  __shared__ float gt[32 * 36];              // gate tile [b_local][pc_local]
  __shared__ _Float16 hlds[256];             // staged h outputs (block-linear = tid)
  const int tid = threadIdx.x;
  const int lane = tid & 63;
  const int w = tid >> 6;                    // 4 waves
  const int wm = w & 1, wn = w >> 1;
  const int blk = blockIdx.x;
  const int mb = blk & 1, nb = blk >> 1;
  const int KB = kxb + 32;
  const int ntg = 2 * nb + wn;

  {  // stage U-part B-fragments for the block's two n-tiles
    #pragma unroll
    for (int h = 0; h < 2; ++h) {
      const uint4* s = (const uint4*)bfrag + (size_t)((2 * nb + h) * KB + kxb) * 64;
      uint4* d = (uint4*)Bs + h * 2048;
      for (int i = tid; i < 2048; i += NT) d[i] = s[i];
    }
  }

  const f16x8* Bxg = (const f16x8*)bfrag;
  const f16x8* Bv  = (const f16x8*)Bs;
  const int q = lane >> 4;
  const int brow = mb * 32 + wm * 16 + (lane & 15);   // global batch this lane supplies (A)
  const int bl = tid >> 3, cl = tid & 7;              // cell-update: batch/col local
  const float bias = biasp[ntg * 16 + (lane & 15)];
  float cc = cin[(size_t)(mb * 32 + bl) * 1024 + 8 * nb + cl];  // register-resident cell
  const u64 hstBase = (u64)(nb * 128 + mb * 64);      // u64 index of block's h span
  const u64* fp = (const u64*)bar + mb * 64 + lane;   // this half's 128 flags (2 per lane)
  __syncthreads();

  // prologue: x-part of step 0 (h-independent)
  f32x4 acc = {bias, bias, bias, bias};
  {
    const f16x8* ax = (const f16x8*)xsrc;
    #pragma unroll 8
    for (int kb = 0; kb < kxb; ++kb)
      acc = __builtin_amdgcn_mfma_f32_16x16x32_f16(ax[(kb * 4 + q) * 64 + brow],
                                                   Bxg[(ntg * KB + kb) * 64 + lane], acc, 0, 0, 0);
  }

  for (int t = 0; t < 256; ++t) {
    if (t) {  // per-wave: wait until all 128 producers of this half published step t
      for (;;) {
        u64 v = __hip_atomic_load(fp, __ATOMIC_RELAXED, __HIP_MEMORY_SCOPE_AGENT);
        if (__all(((int)v >= t) && ((int)(v >> 32) >= t))) break;
        __builtin_amdgcn_s_sleep(1);
      }
      __atomic_signal_fence(__ATOMIC_SEQ_CST);  // keep h loads below the poll
    }

    // h-part (recurrent): coherent loads (remote blocks wrote via sc1)
    const _Float16* hb = (t == 0) ? hinit : (hseq + (size_t)t * 65536);
    #pragma unroll 8
    for (int kb = 0; kb < 32; ++kb) {
      f16x8 a = load_frag_coh(hb + (((kb * 4 + q) << 6) + brow) * 8);
      acc = __builtin_amdgcn_mfma_f32_16x16x32_f16(a, Bv[(wn * 32 + kb) * 64 + lane], acc, 0, 0, 0);
    }

    // C layout: col=lane&15, row=(lane>>4)*4+r -> park in LDS as [b_local][pc_local]
    #pragma unroll
    for (int r = 0; r < 4; ++r)
      gt[(wm * 16 + q * 4 + r) * 36 + wn * 16 + (lane & 15)] = acc[r];
    __syncthreads();
    float4 gv = *(float4*)&gt[bl * 36 + cl * 4];       // i,f,g,o for this thread's cell
    cc = sigm(gv.y) * cc + sigm(gv.x) * tanh_f(gv.z);
    float hn = sigm(gv.w) * tanh_f(cc);
    hlds[tid] = (_Float16)hn;
    __syncthreads();

    // wave 0: publish the block's 512B h span (sc1), drain, then raise the flag
    if (w == 0) {
      u64 v = ((const u64*)hlds)[lane];
      __hip_atomic_store((u64*)(hseq + (size_t)(t + 1) * 65536) + hstBase + lane, v,
                         __ATOMIC_RELAXED, __HIP_MEMORY_SCOPE_AGENT);
      if (t < 255) {
        __builtin_amdgcn_s_waitcnt(0);                  // h stores acked at coherence point
        __atomic_signal_fence(__ATOMIC_SEQ_CST);
        if (lane == 0)
          __hip_atomic_store(&bar[mb * 128 + nb], t + 1, __ATOMIC_RELAXED, __HIP_MEMORY_SCOPE_AGENT);
      }
    }

    if (t < 255) {  // overlap everyone's publish with the h-independent x-part of t+1
      f32x4 a2 = {bias, bias, bias, bias};
      const f16x8* ax = (const f16x8*)(xsrc + (size_t)(t + 1) * xts);
      #pragma unroll 8
      for (int kb = 0; kb < kxb; ++kb)
        a2 = __builtin_amdgcn_mfma_f32_16x16x32_f16(ax[(kb * 4 + q) * 64 + brow],
                                                    Bxg[(ntg * KB + kb) * 64 + lane], a2, 0, 0, 0);
      acc = a2;
    }
  }
  if (cout) cout[(size_t)(mb * 32 + bl) * 1024 + 8 * nb + cl] = cc;
}

// ---------------- FC head ----------------

// Y1[b][u][j] = ys2[u+1][b][:] @ fc1_w[:, j] + fc1_b[j]   (16384x1024 @ 1024x512)
__launch_bounds__(256, 1)
__global__ void fc1_gemm_kernel(const _Float16* __restrict__ ys2, const _Float16* __restrict__ wfrag,
                                const float* __restrict__ fc1b, float* __restrict__ Y1) {
  const int mb = blockIdx.x >> 3;
  const int nb = blockIdx.x & 7;
  const int tid = threadIdx.x;
  const int lane = tid & 63;
  const int w = tid >> 6;
  const int q = lane >> 4;
  const int R0 = mb * 64 + w * 16;
  const int arow = R0 + (lane & 15);           // row = u*64 + b
  const int u = arow >> 6;
  const int b = arow & 63;
  const f16x8* A = (const f16x8*)(ys2 + (size_t)(u + 1) * 65536);  // tiled [cg][b][8]
  const f16x8* W = (const f16x8*)wfrag;
  f32x4 acc[4];
  #pragma unroll
  for (int n = 0; n < 4; ++n) acc[n] = (f32x4){0.f, 0.f, 0.f, 0.f};
  #pragma unroll 4
  for (int kb = 0; kb < 32; ++kb) {
    f16x8 a = A[(kb * 4 + q) * 64 + b];
    #pragma unroll
    for (int n = 0; n < 4; ++n)
      acc[n] = __builtin_amdgcn_mfma_f32_16x16x32_f16(a, W[(((nb * 4 + n) * 32) + kb) * 64 + lane],
                                                      acc[n], 0, 0, 0);
  }
  const int rb = R0 + (q << 2);
  #pragma unroll
  for (int n = 0; n < 4; ++n) {
    int col = nb * 64 + n * 16 + (lane & 15);
    float bias = fc1b[col];
    #pragma unroll
    for (int r = 0; r < 4; ++r) {
      int R = rb + r;
      Y1[((size_t)(R & 63) * 256 + (R >> 6)) * 512 + col] = acc[n][r] + bias;
    }
  }
}

// FC2 partial reduction: 256 K-chunks of 512; part[kc][b][36]
__global__ void fc2_partial_kernel(const float* __restrict__ Y1, const float* __restrict__ fc2w,
                                   float* __restrict__ part) {
  int kc = blockIdx.x;
  int tid = threadIdx.x;
  int b = tid >> 2, qq = tid & 3;
  const float* y = Y1 + (size_t)b * 131072 + (size_t)kc * 512;
  const float* wbase = fc2w + (size_t)kc * 512 * 36 + qq * 9;
  float acc[9];
  #pragma unroll
  for (int j = 0; j < 9; ++j) acc[j] = 0.f;
  for (int k = 0; k < 512; ++k) {
    float yv = y[k];
    const float* wr = wbase + (size_t)k * 36;
    #pragma unroll
    for (int j = 0; j < 9; ++j) acc[j] = fmaf(yv, wr[j], acc[j]);
  }
  float* o = part + ((size_t)kc * 64 + b) * 36 + qq * 9;
  #pragma unroll
  for (int j = 0; j < 9; ++j) o[j] = acc[j];
}

__global__ void fc_final_kernel(const float* __restrict__ part, const float* __restrict__ fc2b,
                                const float* __restrict__ fc3w, const float* __restrict__ fc3b,
                                const float* __restrict__ fc4w, const float* __restrict__ fc4b,
                                float* __restrict__ out) {
  __shared__ float z2[64 * 36];
  __shared__ float z3[64 * 6];
  int tid = threadIdx.x;  // 384
  for (int idx = tid; idx < 64 * 36; idx += 384) {
    int b = idx / 36, m = idx % 36;
    float s = fc2b[m];
    for (int kc = 0; kc < 256; ++kc) s += part[((size_t)kc * 64 + b) * 36 + m];
    z2[idx] = s;
  }
  __syncthreads();
  {
    int b = tid / 6, n = tid % 6;
    float s = fc3b[n];
    #pragma unroll 4
    for (int m = 0; m < 36; ++m) s += z2[b * 36 + m] * fc3w[m * 6 + n];
    z3[tid] = s;
  }
  __syncthreads();
  {
    int b = tid / 6, n = tid % 6;
    float s = fc4b[n];
    #pragma unroll
    for (int m = 0; m < 6; ++m) s += z3[b * 6 + m] * fc4w[m * 6 + n];
    out[tid] = fmaxf(s, 0.0f);
  }
}

// ---------------- host ----------------

extern "C" void kernel_launch(void* const* d_in, const int* in_sizes, int n_in,
                              void* d_out, int out_size, void* d_ws, size_t ws_size,
                              hipStream_t stream) {
  const float* x    = (const float*)d_in[0];
  const float* h0   = (const float*)d_in[1];
  const float* c0   = (const float*)d_in[2];
  const float* W1   = (const float*)d_in[3];
  const float* U1   = (const float*)d_in[4];
  const float* b1   = (const float*)d_in[5];
  const float* W2   = (const float*)d_in[6];
  const float* U2   = (const float*)d_in[7];
  const float* b2   = (const float*)d_in[8];
  const float* fc1w = (const float*)d_in[9];
  const float* fc1b = (const float*)d_in[10];
  const float* fc2w = (const float*)d_in[11];
  const float* fc2b = (const float*)d_in[12];
  const float* fc3w = (const float*)d_in[13];
  const float* fc3b = (const float*)d_in[14];
  const float* fc4w = (const float*)d_in[15];
  const float* fc4b = (const float*)d_in[16];
  float* out = (float*)d_out;

  char* p = (char*)d_ws;
  auto alloc = [&](size_t bytes) { char* r = p; p += (bytes + 255) & ~(size_t)255; return r; };
  _Float16* xh    = (_Float16*)alloc(8388608ull * 2);        // x tiled f16 [t][dg][b][8]
  _Float16* wu1f  = (_Float16*)alloc(1536ull * 4096 * 2);    // [W1;U1] B-fragments, permuted cols
  _Float16* wu2f  = (_Float16*)alloc(2048ull * 4096 * 2);    // [W2;U2]
  _Float16* fc1wf = (_Float16*)alloc(1024ull * 512 * 2);     // fc1_w B-fragments
  float* b1p      = (float*)alloc(4096 * 4);
  float* b2p      = (float*)alloc(4096 * 4);
  _Float16* ys1   = (_Float16*)alloc(257ull * 65536 * 2);    // h1 slots, tiled: [0]=h0, [t+1]=h1_t
  _Float16* ys2   = (_Float16*)alloc(257ull * 65536 * 2);    // h2 slots, tiled
  float* cfin     = (float*)alloc(65536 * 4);                // c1 final [b][h] fp32
  float* Y1       = (float*)alloc(8388608ull * 4);           // FC1 out, [b][u][j] fp32
  float* part     = (float*)alloc(256ull * 64 * 36 * 4);     // FC2 partials
  int* bar        = (int*)alloc(8192 * 4);                   // 2 flag regions (2048 ints each)
  (void)in_sizes; (void)n_in; (void)out_size; (void)ws_size;

  prep_x_kernel<<<8388608 / 256, 256, 0, stream>>>(x, xh);
  swizzle_b_kernel<<<(256 * 48 * 64) / 256, 256, 0, stream>>>(W1, U1, 512, 1536, 4096, 4096, 1, wu1f);
  swizzle_b_kernel<<<(256 * 64 * 64) / 256, 256, 0, stream>>>(W2, U2, 1024, 2048, 4096, 4096, 1, wu2f);
  swizzle_b_kernel<<<(32 * 32 * 64) / 256, 256, 0, stream>>>(fc1w, fc1w, 1024, 1024, 512, 512, 0, fc1wf);
  prep_small_kernel<<<256, 256, 0, stream>>>(b1, b2, h0, b1p, b2p, ys1, bar);

  // Layer 1: x from xh (t-stride 32768 f16), 16 x-kblks; h slot0 = h0; c: c0 -> cfin
  lstm_layer_kernel<<<256, NT, 0, stream>>>(
      xh, (size_t)32768, 16, ys1, ys1, wu1f, b1p, c0, cfin, bar);
  // Layer 2: x = ys1 slots 1..256 (t-stride 65536), 32 x-kblks; h init = ys1 slot 256; c from cfin
  lstm_layer_kernel<<<256, NT, 0, stream>>>(
      ys1 + 65536, (size_t)65536, 32, ys2, ys1 + (size_t)256 * 65536, wu2f, b2p, cfin, nullptr, bar + 2048);

  fc1_gemm_kernel<<<2048, 256, 0, stream>>>(ys2, fc1wf, fc1b, Y1);
  fc2_partial_kernel<<<256, 256, 0, stream>>>(Y1, fc2w, part);
  fc_final_kernel<<<1, 384, 0, stream>>>(part, fc2b, fc3w, fc3b, fc4w, fc4b, out);
}

// Round 5
// 5698.692 us; speedup vs baseline: 2.5406x; 1.0322x over previous
//
#include <hip/hip_runtime.h>

// ComplexModel: 2-layer LSTM (B=64,T=256,D=512,H=1024) + FC head, MI355X gfx950.
// R5: L2-filtered h broadcast. h slot lines are single-writer, read-after-flag,
// and all stale pre-dispatch cache lines are purged by a one-time agent acquire
// (buffer_inv) per block. So h-part A-fragments use PLAIN cached loads: the
// per-XCD L2 turns the 32 MB/step chip-wide sc1 broadcast (R3/R4's hidden
// bottleneck) into ~1 MB/step of LLC traffic + L2 hits.
// Producer path unchanged: wave0 sc1-stores the block's 512B h span, drains,
// raises a per-block flag; consumers poll flags (sc1) per-wave.

#define NT 256

typedef _Float16 f16x8 __attribute__((ext_vector_type(8)));
typedef float f32x4 __attribute__((ext_vector_type(4)));
typedef unsigned long long u64;

__device__ __forceinline__ float sigm(float x)   { return 1.0f / (1.0f + __expf(-x)); }
__device__ __forceinline__ float tanh_f(float x) { return 1.0f - 2.0f / (__expf(2.0f * x) + 1.0f); }

// ---------------- prep kernels ----------------

// x [b][t][d] fp32 -> xh tiled f16: xh[t][dg=d/8][b][d%8]
__global__ void prep_x_kernel(const float* __restrict__ x, _Float16* __restrict__ xh) {
  int id = blockIdx.x * blockDim.x + threadIdx.x;   // 64*256*512
  int j = id & 7, b = (id >> 3) & 63, cg = (id >> 9) & 63, t = id >> 15;
  xh[id] = (_Float16)x[((size_t)b * 256 + t) * 512 + cg * 8 + j];
}

// Build MFMA B-fragment layout: dst[((nt*(K/32)+kb)*64 + lane)*8 + j] =
//   src[k = kb*32 + (lane>>4)*8 + j][col = perm(nt*16 + (lane&15))]
__global__ void swizzle_b_kernel(const float* __restrict__ src0, const float* __restrict__ src1,
                                 int k0, int K, int N, int srcStride, int permute,
                                 _Float16* __restrict__ dst) {
  int id = blockIdx.x * blockDim.x + threadIdx.x;
  int total = (N / 16) * (K / 32) * 64;
  if (id >= total) return;
  int lane = id & 63;
  int kb = (id >> 6) % (K / 32);
  int nt = id / ((K / 32) * 64);
  int kbase = kb * 32 + ((lane >> 4) << 3);
  int pc = nt * 16 + (lane & 15);
  int oc = permute ? ((pc & 3) * 1024 + (pc >> 2)) : pc;   // pc = 4*hcol + gate
  f16x8 v;
  #pragma unroll
  for (int j = 0; j < 8; ++j) {
    int k = kbase + j;
    float f = (k < k0) ? src0[(size_t)k * srcStride + oc]
                       : src1[(size_t)(k - k0) * srcStride + oc];
    v[j] = (_Float16)f;
  }
  ((f16x8*)dst)[id] = v;
}

__global__ void prep_small_kernel(const float* __restrict__ b1, const float* __restrict__ b2,
                                  const float* __restrict__ h0,
                                  float* __restrict__ b1p, float* __restrict__ b2p,
                                  _Float16* __restrict__ ys1_0, int* __restrict__ bar) {
  int i = blockIdx.x * blockDim.x + threadIdx.x;
  if (i < 4096) {
    int oc = (i & 3) * 1024 + (i >> 2);
    b1p[i] = b1[oc];
    b2p[i] = b2[oc];
  }
  if (i < 65536) {  // h0 [b][1024] -> tiled [cg][b][8]
    int j = i & 7, b = (i >> 3) & 63, cg = i >> 9;
    ys1_0[i] = (_Float16)h0[b * 1024 + cg * 8 + j];
  }
  if (i < 8192) bar[i] = 0;
}

// ---------------- persistent LSTM layer ----------------
// Grid 256 = mb(2) x nb(128). Block owns batches [32mb,32mb+32) x hcols [8nb,8nb+8)
// = permuted gate cols [32nb,32nb+32) = n-tiles {2nb,2nb+1}. 4 waves: wm=w&1 (m-tile),
// wn=w>>1 (n-tile). h slot layout: [cg=col/8][b][col%8].
// Sync: flags bar[mb*128 + nb] monotonic = last published step+1.
__launch_bounds__(NT, 1)
__global__ void lstm_layer_kernel(const _Float16* __restrict__ xsrc, size_t xts, int kxb,
                                  _Float16* hseq, const _Float16* __restrict__ hinit,
                                  const _Float16* __restrict__ bfrag, const float* __restrict__ biasp,
                                  const float* __restrict__ cin, float* __restrict__ cout,
                                  int* bar) {
  __shared__ _Float16 Bs[2 * 32 * 64 * 8];   // 64 KB: U-part B fragments, 2 n-tiles
  __shared__ float gt[32 * 36];              // gate tile [b_local][pc_local]
  __shared__ _Float16 hlds[256];             // staged h outputs (block-linear = tid)
  const int tid = threadIdx.x;
  const int lane = tid & 63;
  const int w = tid >> 6;                    // 4 waves
  const int wm = w & 1, wn = w >> 1;
  const int blk = blockIdx.x;
  const int mb = blk & 1, nb = blk >> 1;
  const int KB = kxb + 32;
  const int ntg = 2 * nb + wn;

  // One-time device-scope acquire: buffer_inv purges stale L1/L2 lines (e.g. the
  // harness's 0xAA poison blit) so plain cached loads of h slots are coherent.
  if (tid == 0)
    (void)__hip_atomic_load(&bar[1024], __ATOMIC_ACQUIRE, __HIP_MEMORY_SCOPE_AGENT);
  __syncthreads();

  {  // stage U-part B-fragments for the block's two n-tiles
    #pragma unroll
    for (int h = 0; h < 2; ++h) {
      const uint4* s = (const uint4*)bfrag + (size_t)((2 * nb + h) * KB + kxb) * 64;
      uint4* d = (uint4*)Bs + h * 2048;
      for (int i = tid; i < 2048; i += NT) d[i] = s[i];
    }
  }

  const f16x8* Bxg = (const f16x8*)bfrag;
  const f16x8* Bv  = (const f16x8*)Bs;
  const int q = lane >> 4;
  const int brow = mb * 32 + wm * 16 + (lane & 15);   // global batch this lane supplies (A)
  const int bl = tid >> 3, cl = tid & 7;              // cell-update: batch/col local
  const float bias = biasp[ntg * 16 + (lane & 15)];
  float cc = cin[(size_t)(mb * 32 + bl) * 1024 + 8 * nb + cl];  // register-resident cell
  const u64 hstBase = (u64)(nb * 128 + mb * 64);      // u64 index of block's h span
  const u64* fp = (const u64*)bar + mb * 64 + lane;   // this half's 128 flags (2 per lane)
  __syncthreads();

  // prologue: x-part of step 0 (h-independent)
  f32x4 acc = {bias, bias, bias, bias};
  {
    const f16x8* ax = (const f16x8*)xsrc;
    #pragma unroll 8
    for (int kb = 0; kb < kxb; ++kb)
      acc = __builtin_amdgcn_mfma_f32_16x16x32_f16(ax[(kb * 4 + q) * 64 + brow],
                                                   Bxg[(ntg * KB + kb) * 64 + lane], acc, 0, 0, 0);
  }

  for (int t = 0; t < 256; ++t) {
    if (t) {  // per-wave: wait until all 128 producers of this half published step t
      for (;;) {
        u64 v = __hip_atomic_load(fp, __ATOMIC_RELAXED, __HIP_MEMORY_SCOPE_AGENT);
        if (__all(((int)v >= t) && ((int)(v >> 32) >= t))) break;
        __builtin_amdgcn_s_sleep(1);
      }
      asm volatile("" ::: "memory");  // keep the h loads below the poll
    }

    // h-part (recurrent): PLAIN cached loads — single-writer lines, read-after-flag,
    // caches purged at start => coherent; per-XCD L2 filters the broadcast.
    const f16x8* ah = (const f16x8*)((t == 0) ? hinit : (hseq + (size_t)t * 65536));
    #pragma unroll 8
    for (int kb = 0; kb < 32; ++kb)
      acc = __builtin_amdgcn_mfma_f32_16x16x32_f16(ah[(kb * 4 + q) * 64 + brow],
                                                   Bv[(wn * 32 + kb) * 64 + lane], acc, 0, 0, 0);

    // C layout: col=lane&15, row=(lane>>4)*4+r -> park in LDS as [b_local][pc_local]
    #pragma unroll
    for (int r = 0; r < 4; ++r)
      gt[(wm * 16 + q * 4 + r) * 36 + wn * 16 + (lane & 15)] = acc[r];
    __syncthreads();
    float4 gv = *(float4*)&gt[bl * 36 + cl * 4];       // i,f,g,o for this thread's cell
    cc = sigm(gv.y) * cc + sigm(gv.x) * tanh_f(gv.z);
    float hn = sigm(gv.w) * tanh_f(cc);
    hlds[tid] = (_Float16)hn;
    __syncthreads();

    // wave 0: publish the block's 512B h span (sc1 write-through), drain, raise flag
    if (w == 0) {
      u64 v = ((const u64*)hlds)[lane];
      __hip_atomic_store((u64*)(hseq + (size_t)(t + 1) * 65536) + hstBase + lane, v,
                         __ATOMIC_RELAXED, __HIP_MEMORY_SCOPE_AGENT);
      if (t < 255) {
        __builtin_amdgcn_s_waitcnt(0);                  // h stores acked at coherence point
        asm volatile("" ::: "memory");
        if (lane == 0)
          __hip_atomic_store(&bar[mb * 128 + nb], t + 1, __ATOMIC_RELAXED, __HIP_MEMORY_SCOPE_AGENT);
      }
    }

    if (t < 255) {  // overlap everyone's publish with the h-independent x-part of t+1
      f32x4 a2 = {bias, bias, bias, bias};
      const f16x8* ax = (const f16x8*)(xsrc + (size_t)(t + 1) * xts);
      #pragma unroll 8
      for (int kb = 0; kb < kxb; ++kb)
        a2 = __builtin_amdgcn_mfma_f32_16x16x32_f16(ax[(kb * 4 + q) * 64 + brow],
                                                    Bxg[(ntg * KB + kb) * 64 + lane], a2, 0, 0, 0);
      acc = a2;
    }
  }
  if (cout) cout[(size_t)(mb * 32 + bl) * 1024 + 8 * nb + cl] = cc;
}

// ---------------- FC head ----------------

// Y1[b][u][j] = ys2[u+1][b][:] @ fc1_w[:, j] + fc1_b[j]   (16384x1024 @ 1024x512)
__launch_bounds__(256, 1)
__global__ void fc1_gemm_kernel(const _Float16* __restrict__ ys2, const _Float16* __restrict__ wfrag,
                                const float* __restrict__ fc1b, float* __restrict__ Y1) {
  const int mb = blockIdx.x >> 3;
  const int nb = blockIdx.x & 7;
  const int tid = threadIdx.x;
  const int lane = tid & 63;
  const int w = tid >> 6;
  const int q = lane >> 4;
  const int R0 = mb * 64 + w * 16;
  const int arow = R0 + (lane & 15);           // row = u*64 + b
  const int u = arow >> 6;
  const int b = arow & 63;
  const f16x8* A = (const f16x8*)(ys2 + (size_t)(u + 1) * 65536);  // tiled [cg][b][8]
  const f16x8* W = (const f16x8*)wfrag;
  f32x4 acc[4];
  #pragma unroll
  for (int n = 0; n < 4; ++n) acc[n] = (f32x4){0.f, 0.f, 0.f, 0.f};
  #pragma unroll 4
  for (int kb = 0; kb < 32; ++kb) {
    f16x8 a = A[(kb * 4 + q) * 64 + b];
    #pragma unroll
    for (int n = 0; n < 4; ++n)
      acc[n] = __builtin_amdgcn_mfma_f32_16x16x32_f16(a, W[(((nb * 4 + n) * 32) + kb) * 64 + lane],
                                                      acc[n], 0, 0, 0);
  }
  const int rb = R0 + (q << 2);
  #pragma unroll
  for (int n = 0; n < 4; ++n) {
    int col = nb * 64 + n * 16 + (lane & 15);
    float bias = fc1b[col];
    #pragma unroll
    for (int r = 0; r < 4; ++r) {
      int R = rb + r;
      Y1[((size_t)(R & 63) * 256 + (R >> 6)) * 512 + col] = acc[n][r] + bias;
    }
  }
}

// FC2 partial reduction: 256 K-chunks of 512; part[kc][b][36]
__global__ void fc2_partial_kernel(const float* __restrict__ Y1, const float* __restrict__ fc2w,
                                   float* __restrict__ part) {
  int kc = blockIdx.x;
  int tid = threadIdx.x;
  int b = tid >> 2, qq = tid & 3;
  const float* y = Y1 + (size_t)b * 131072 + (size_t)kc * 512;
  const float* wbase = fc2w + (size_t)kc * 512 * 36 + qq * 9;
  float acc[9];
  #pragma unroll
  for (int j = 0; j < 9; ++j) acc[j] = 0.f;
  for (int k = 0; k < 512; ++k) {
    float yv = y[k];
    const float* wr = wbase + (size_t)k * 36;
    #pragma unroll
    for (int j = 0; j < 9; ++j) acc[j] = fmaf(yv, wr[j], acc[j]);
  }
  float* o = part + ((size_t)kc * 64 + b) * 36 + qq * 9;
  #pragma unroll
  for (int j = 0; j < 9; ++j) o[j] = acc[j];
}

__global__ void fc_final_kernel(const float* __restrict__ part, const float* __restrict__ fc2b,
                                const float* __restrict__ fc3w, const float* __restrict__ fc3b,
                                const float* __restrict__ fc4w, const float* __restrict__ fc4b,
                                float* __restrict__ out) {
  __shared__ float z2[64 * 36];
  __shared__ float z3[64 * 6];
  int tid = threadIdx.x;  // 384
  for (int idx = tid; idx < 64 * 36; idx += 384) {
    int b = idx / 36, m = idx % 36;
    float s = fc2b[m];
    for (int kc = 0; kc < 256; ++kc) s += part[((size_t)kc * 64 + b) * 36 + m];
    z2[idx] = s;
  }
  __syncthreads();
  {
    int b = tid / 6, n = tid % 6;
    float s = fc3b[n];
    #pragma unroll 4
    for (int m = 0; m < 36; ++m) s += z2[b * 36 + m] * fc3w[m * 6 + n];
    z3[tid] = s;
  }
  __syncthreads();
  {
    int b = tid / 6, n = tid % 6;
    float s = fc4b[n];
    #pragma unroll
    for (int m = 0; m < 6; ++m) s += z3[b * 6 + m] * fc4w[m * 6 + n];
    out[tid] = fmaxf(s, 0.0f);
  }
}

// ---------------- host ----------------

extern "C" void kernel_launch(void* const* d_in, const int* in_sizes, int n_in,
                              void* d_out, int out_size, void* d_ws, size_t ws_size,
                              hipStream_t stream) {
  const float* x    = (const float*)d_in[0];
  const float* h0   = (const float*)d_in[1];
  const float* c0   = (const float*)d_in[2];
  const float* W1   = (const float*)d_in[3];
  const float* U1   = (const float*)d_in[4];
  const float* b1   = (const float*)d_in[5];
  const float* W2   = (const float*)d_in[6];
  const float* U2   = (const float*)d_in[7];
  const float* b2   = (const float*)d_in[8];
  const float* fc1w = (const float*)d_in[9];
  const float* fc1b = (const float*)d_in[10];
  const float* fc2w = (const float*)d_in[11];
  const float* fc2b = (const float*)d_in[12];
  const float* fc3w = (const float*)d_in[13];
  const float* fc3b = (const float*)d_in[14];
  const float* fc4w = (const float*)d_in[15];
  const float* fc4b = (const float*)d_in[16];
  float* out = (float*)d_out;

  char* p = (char*)d_ws;
  auto alloc = [&](size_t bytes) { char* r = p; p += (bytes + 255) & ~(size_t)255; return r; };
  _Float16* xh    = (_Float16*)alloc(8388608ull * 2);        // x tiled f16 [t][dg][b][8]
  _Float16* wu1f  = (_Float16*)alloc(1536ull * 4096 * 2);    // [W1;U1] B-fragments, permuted cols
  _Float16* wu2f  = (_Float16*)alloc(2048ull * 4096 * 2);    // [W2;U2]
  _Float16* fc1wf = (_Float16*)alloc(1024ull * 512 * 2);     // fc1_w B-fragments
  float* b1p      = (float*)alloc(4096 * 4);
  float* b2p      = (float*)alloc(4096 * 4);
  _Float16* ys1   = (_Float16*)alloc(257ull * 65536 * 2);    // h1 slots, tiled: [0]=h0, [t+1]=h1_t
  _Float16* ys2   = (_Float16*)alloc(257ull * 65536 * 2);    // h2 slots, tiled
  float* cfin     = (float*)alloc(65536 * 4);                // c1 final [b][h] fp32
  float* Y1       = (float*)alloc(8388608ull * 4);           // FC1 out, [b][u][j] fp32
  float* part     = (float*)alloc(256ull * 64 * 36 * 4);     // FC2 partials
  int* bar        = (int*)alloc(8192 * 4);                   // 2 flag regions (2048 ints each)
  (void)in_sizes; (void)n_in; (void)out_size; (void)ws_size;

  prep_x_kernel<<<8388608 / 256, 256, 0, stream>>>(x, xh);
  swizzle_b_kernel<<<(256 * 48 * 64) / 256, 256, 0, stream>>>(W1, U1, 512, 1536, 4096, 4096, 1, wu1f);
  swizzle_b_kernel<<<(256 * 64 * 64) / 256, 256, 0, stream>>>(W2, U2, 1024, 2048, 4096, 4096, 1, wu2f);
  swizzle_b_kernel<<<(32 * 32 * 64) / 256, 256, 0, stream>>>(fc1w, fc1w, 1024, 1024, 512, 512, 0, fc1wf);
  prep_small_kernel<<<256, 256, 0, stream>>>(b1, b2, h0, b1p, b2p, ys1, bar);

  // Layer 1: x from xh (t-stride 32768 f16), 16 x-kblks; h slot0 = h0; c: c0 -> cfin
  lstm_layer_kernel<<<256, NT, 0, stream>>>(
      xh, (size_t)32768, 16, ys1, ys1, wu1f, b1p, c0, cfin, bar);
  // Layer 2: x = ys1 slots 1..256 (t-stride 65536), 32 x-kblks; h init = ys1 slot 256; c from cfin
  lstm_layer_kernel<<<256, NT, 0, stream>>>(
      ys1 + 65536, (size_t)65536, 32, ys2, ys1 + (size_t)256 * 65536, wu2f, b2p, cfin, nullptr, bar + 2048);

  fc1_gemm_kernel<<<2048, 256, 0, stream>>>(ys2, fc1wf, fc1b, Y1);
  fc2_partial_kernel<<<256, 256, 0, stream>>>(Y1, fc2w, part);
  fc_final_kernel<<<1, 384, 0, stream>>>(part, fc2b, fc3w, fc3b, fc4w, fc4b, out);
}